// Round 4
// baseline (267.781 us; speedup 1.0000x reference)
//
#include <hip/hip_runtime.h>
#include <math.h>

// Problem constants (B, N, D2, S = 64, 4096, 128, 512)
#define BB 64
#define NN 4096
#define DD 128
#define SS 512
#define CHUNKS 16          // blocks per b
#define RPC 256            // rows per chunk = NN / CHUNKS
#define SUBT 4             // 64-row subtiles per chunk

// ---------------------------------------------------------------------------
// Fused kernel v6: stream-first structure. All 32 float4 chunk loads issue at
// block start (512 B/thread in registers, sched_barrier-pinned above the
// q-phase). The q = yq@w phase then runs with NO vmcnt drain: yq is read
// directly from global (uniform -> s_loads), and the single LDS-visibility
// barrier for qsh is a manual {s_waitcnt lgkmcnt(0); s_barrier} pair, so the
// in-flight y_past loads cross the barrier untouched (__syncthreads would
// emit s_waitcnt vmcnt(0) and serialize the stream behind the q-phase --
// the structural flaw shared by v0/v2/v4, all ~same dur).
// launch_bounds(256,2): VGPR cap 256 (need ~190 for the 32-deep prefetch),
// 2 blocks/CU = 8 waves/CU; in-flight 262 KB/CU >> 9.2 KB latency-BW product.
// ---------------------------------------------------------------------------
__global__ __launch_bounds__(256, 2) void fused_kernel(
    const float* __restrict__ y_past, const float* __restrict__ yq,
    const float* __restrict__ w, const int* __restrict__ s_past,
    float* __restrict__ bins_g, float* __restrict__ pmax) {
    const int b = blockIdx.x, chunk = blockIdx.y;
    const int t = threadIdx.x;
    const int j = t & 3;   // quarter of row (32 floats)
    const int r = t >> 2;  // row within 64-row subtile

    __shared__ float qsh[DD];
    __shared__ float bins[SS];
    __shared__ float wred[8];

    const float4* gp =
        (const float4*)y_past + ((size_t)b * NN + (size_t)chunk * RPC) * 32;

    // ---- 1. issue the ENTIRE chunk's loads up front (32 float4 / thread) ----
    float4 yv[SUBT][8];
#pragma unroll
    for (int s = 0; s < SUBT; ++s)
#pragma unroll
        for (int k = 0; k < 8; ++k)
            yv[s][k] = gp[(size_t)(s * 64 + r) * 32 + j * 8 + k];

    int sreg[SUBT];
    if (j == 0) {
#pragma unroll
        for (int s = 0; s < SUBT; ++s)
            sreg[s] = s_past[(size_t)b * NN + chunk * RPC + s * 64 + r];
    }

    bins[t] = 0.f;
    bins[t + 256] = 0.f;

    // pin: nothing from the q-phase may be hoisted above the stream issue,
    // and the stream issue may not sink below.
    __builtin_amdgcn_sched_barrier(0);

    // ---- 2. q = yq @ w (threads 0..127; yq uniform -> scalar loads;
    //         w coalesced, L2-resident). No LDS staging of yq -> no barrier
    //         needed before this phase.
    if (t < DD) {
        const float* yqb = yq + b * DD;
        float acc = 0.f;
#pragma unroll
        for (int d = 0; d < DD; ++d) acc = fmaf(yqb[d], w[d * DD + t], acc);
        qsh[t] = acc;
    }

    // ---- 3. LDS-visibility barrier WITHOUT the vmcnt(0) drain ----
    asm volatile("s_waitcnt lgkmcnt(0)" ::: "memory");
    __builtin_amdgcn_s_barrier();

    // ---- 4. read q fragment (broadcast within j-groups, conflict-free) ----
    float4 qreg[8];
#pragma unroll
    for (int k = 0; k < 8; ++k) qreg[k] = ((const float4*)qsh)[j * 8 + k];

    // ---- 5. dot products; compiler inserts counted vmcnt waits as the
    //         prefetched yv registers are consumed ----
    float pv[SUBT];
#pragma unroll
    for (int s = 0; s < SUBT; ++s) {
        float4 acc = {0.f, 0.f, 0.f, 0.f};
#pragma unroll
        for (int k = 0; k < 8; ++k) {
            acc.x = fmaf(qreg[k].x, yv[s][k].x, acc.x);
            acc.y = fmaf(qreg[k].y, yv[s][k].y, acc.y);
            acc.z = fmaf(qreg[k].z, yv[s][k].z, acc.z);
            acc.w = fmaf(qreg[k].w, yv[s][k].w, acc.w);
        }
        float p = (acc.x + acc.y) + (acc.z + acc.w);
        p += __shfl_xor(p, 1, 64);
        p += __shfl_xor(p, 2, 64);  // all 4 lanes of row-group hold full dot
        pv[s] = p;
    }

    // ---- 6. chunk max over 256 rows (vmcnt naturally drained by now;
    //         full __syncthreads is fine and also orders bins zeroing) ----
    float m = fmaxf(fmaxf(pv[0], pv[1]), fmaxf(pv[2], pv[3]));
#pragma unroll
    for (int off = 32; off > 0; off >>= 1) m = fmaxf(m, __shfl_xor(m, off, 64));
    const int wave = t >> 6, lane = t & 63;
    if (lane == 0) wred[wave] = m;
    __syncthreads();
    m = fmaxf(fmaxf(wred[0], wred[1]), fmaxf(wred[2], wred[3]));

    // ---- 7. scatter exp(p - m_c) into LDS bins (j==0 lane per row group) ----
    if (j == 0) {
#pragma unroll
        for (int s = 0; s < SUBT; ++s)
            atomicAdd(&bins[sreg[s]], __expf(pv[s] - m));
    }
    __syncthreads();

    // ---- 8. write chunk bins + max ----
    float* bg = bins_g + ((size_t)b * CHUNKS + chunk) * SS;
    bg[t] = bins[t];
    bg[t + 256] = bins[t + 256];
    if (t == 0) pmax[b * CHUNKS + chunk] = m;
}

// ---------------------------------------------------------------------------
// Combine: out[b,s] = (sum_c bins[b,c,s] * exp(m_c - M)) / Z,
// Z recovered as the block-wide sum of the numerators. 64 blocks x 512 thr.
// ---------------------------------------------------------------------------
__global__ __launch_bounds__(512) void combine_kernel(
    const float* __restrict__ bins_g, const float* __restrict__ pmax,
    float* __restrict__ out) {
    int b = blockIdx.x;
    int t = threadIdx.x;  // 0..511
    __shared__ float scale[CHUNKS];
    __shared__ float red[8];
    __shared__ float sInv;

    if (t < CHUNKS) scale[t] = pmax[b * CHUNKS + t];
    __syncthreads();
    if (t == 0) {
        float M = scale[0];
#pragma unroll
        for (int c = 1; c < CHUNKS; ++c) M = fmaxf(M, scale[c]);
#pragma unroll
        for (int c = 0; c < CHUNKS; ++c) scale[c] = __expf(scale[c] - M);
    }
    __syncthreads();

    float acc = 0.f;
#pragma unroll
    for (int c = 0; c < CHUNKS; ++c)
        acc = fmaf(bins_g[((size_t)b * CHUNKS + c) * SS + t], scale[c], acc);

    float s = acc;
#pragma unroll
    for (int off = 32; off > 0; off >>= 1) s += __shfl_xor(s, off, 64);
    if ((t & 63) == 0) red[t >> 6] = s;
    __syncthreads();
    if (t == 0) {
        float S = 0.f;
#pragma unroll
        for (int i = 0; i < 8; ++i) S += red[i];
        sInv = 1.f / S;
    }
    __syncthreads();

    out[b * SS + t] = acc * sInv;
}

// ---------------------------------------------------------------------------
// Launch. Inputs: [0]=s_past(int B*N), [1]=yq(f32 B*D2), [2]=y_past(f32
// B*N*D2), [3]=w_mat(f32 D2*D2), [4]=size_s. Out: post_est f32 B*S.
// ws: bins_g (B*CHUNKS*S = 2 MB) | pmax (B*CHUNKS)
// ---------------------------------------------------------------------------
extern "C" void kernel_launch(void* const* d_in, const int* in_sizes, int n_in,
                              void* d_out, int out_size, void* d_ws, size_t ws_size,
                              hipStream_t stream) {
    const int*   s_past = (const int*)d_in[0];
    const float* yq     = (const float*)d_in[1];
    const float* y_past = (const float*)d_in[2];
    const float* w_mat  = (const float*)d_in[3];

    float* ws     = (float*)d_ws;
    float* bins_g = ws;                         // BB*CHUNKS*SS floats
    float* pmax   = bins_g + BB * CHUNKS * SS;  // BB*CHUNKS floats
    float* out    = (float*)d_out;

    fused_kernel<<<dim3(BB, CHUNKS), 256, 0, stream>>>(y_past, yq, w_mat,
                                                       s_past, bins_g, pmax);
    combine_kernel<<<BB, SS, 0, stream>>>(bins_g, pmax, out);
}

// Round 7
// 249.042 us; speedup vs baseline: 1.0752x; 1.0752x over previous
//
#include <hip/hip_runtime.h>
#include <math.h>

// Problem constants (B, N, D2, S = 64, 4096, 128, 512)
#define BB 64
#define NN 4096
#define DD 128
#define SS 512
#define CHUNKS 16          // blocks per b (ws layout unchanged: bins_g = 2 MB)
#define RPC 256            // rows per chunk = NN / CHUNKS
#define SUBT 2             // 128-row subtiles per chunk (512 threads, 4/row)

// ---------------------------------------------------------------------------
// Fused kernel v9: 32-wave/CU experiment, maximally conservative encoding.
//   After two container failures (R5: 4MB-ws variant, R6: asm-barrier
//   variant), this resubmits the SAME residency hypothesis using only
//   constructs proven to execute in this session:
//   - 512-thread blocks with __launch_bounds__(512, 8)   [ran in R3]
//   - grid 64x16, 2 MB workspace                          [ran in R0-R4]
//   - plain __syncthreads() only, NO inline asm, NO raw s_barrier
//   - yq read directly from global in the q-phase (uniform -> s_loads),
//     eliminating R3's syq-staging barrier and qpart-reduce barrier:
//     exactly ONE barrier between block start and the stream loop
//     (R3 had three -- its +10us is attributed to that structure).
//   Hypothesis: per-CU stream BW scales with resident waves
//   (8 w -> 1.13 TB/s [R4], 16 w -> 2.4 TB/s [R1]); 32 waves/CU should cut
//   the fused kernel from ~56us toward ~30us.
// ---------------------------------------------------------------------------
__global__ __launch_bounds__(512, 8) void fused_kernel(
    const float* __restrict__ y_past, const float* __restrict__ yq,
    const float* __restrict__ w, const int* __restrict__ s_past,
    float* __restrict__ bins_g, float* __restrict__ pmax) {
    const int b = blockIdx.x, chunk = blockIdx.y;
    const int t = threadIdx.x;   // 0..511
    const int j = t & 3;         // quarter of row (32 floats)
    const int r = t >> 2;        // row within 128-row subtile

    __shared__ float qsh[DD];
    __shared__ float bins[SS];
    __shared__ float wred[8];

    const float4* gp =
        (const float4*)y_past + ((size_t)b * NN + (size_t)chunk * RPC) * 32;

    // ---- subtile-0 half prefetch + s_past indices (independent of q) ----
    float4 y0[4];
#pragma unroll
    for (int k = 0; k < 4; ++k) y0[k] = gp[(size_t)r * 32 + j * 8 + k];

    int sreg[SUBT];
    if (j == 0) {
#pragma unroll
        for (int s = 0; s < SUBT; ++s)
            sreg[s] = s_past[(size_t)b * NN + chunk * RPC + s * 128 + r];
    }

    bins[t] = 0.f;   // 512 threads cover SS=512

    // ---- q = yq @ w (threads 0..127; yq read directly from global so no
    //      staging barrier; w is L2-resident) ----
    if (t < DD) {
        const float* yqb = yq + b * DD;
        float acc = 0.f;
#pragma unroll
        for (int d = 0; d < DD; ++d) acc = fmaf(yqb[d], w[d * DD + t], acc);
        qsh[t] = acc;
    }

    // ---- the ONE pre-stream barrier ----
    __syncthreads();

    // ---- q fragment (broadcast within j-groups, conflict-free) ----
    float4 qreg[8];
#pragma unroll
    for (int k = 0; k < 8; ++k) qreg[k] = ((const float4*)qsh)[j * 8 + k];

    float pv[SUBT];

    // ---- subtile 0: first half from prefetch regs, second half fresh ----
    {
        float4 acc = {0.f, 0.f, 0.f, 0.f};
#pragma unroll
        for (int k = 0; k < 4; ++k) {
            acc.x = fmaf(qreg[k].x, y0[k].x, acc.x);
            acc.y = fmaf(qreg[k].y, y0[k].y, acc.y);
            acc.z = fmaf(qreg[k].z, y0[k].z, acc.z);
            acc.w = fmaf(qreg[k].w, y0[k].w, acc.w);
        }
#pragma unroll
        for (int k = 4; k < 8; ++k) {
            float4 yv = gp[(size_t)r * 32 + j * 8 + k];
            acc.x = fmaf(qreg[k].x, yv.x, acc.x);
            acc.y = fmaf(qreg[k].y, yv.y, acc.y);
            acc.z = fmaf(qreg[k].z, yv.z, acc.z);
            acc.w = fmaf(qreg[k].w, yv.w, acc.w);
        }
        float p = (acc.x + acc.y) + (acc.z + acc.w);
        p += __shfl_xor(p, 1, 64);
        p += __shfl_xor(p, 2, 64);  // all 4 lanes of row-group hold full dot
        pv[0] = p;
    }

    // ---- subtile 1: straight global->reg, no barriers ----
    {
        float4 acc = {0.f, 0.f, 0.f, 0.f};
#pragma unroll
        for (int k = 0; k < 8; ++k) {
            float4 yv = gp[(size_t)(128 + r) * 32 + j * 8 + k];
            acc.x = fmaf(qreg[k].x, yv.x, acc.x);
            acc.y = fmaf(qreg[k].y, yv.y, acc.y);
            acc.z = fmaf(qreg[k].z, yv.z, acc.z);
            acc.w = fmaf(qreg[k].w, yv.w, acc.w);
        }
        float p = (acc.x + acc.y) + (acc.z + acc.w);
        p += __shfl_xor(p, 1, 64);
        p += __shfl_xor(p, 2, 64);
        pv[1] = p;
    }

    // ---- chunk max over 256 rows (8 waves) ----
    float m = fmaxf(pv[0], pv[1]);
#pragma unroll
    for (int off = 32; off > 0; off >>= 1) m = fmaxf(m, __shfl_xor(m, off, 64));
    const int wave = t >> 6, lane = t & 63;
    if (lane == 0) wred[wave] = m;
    __syncthreads();
    m = fmaxf(fmaxf(fmaxf(wred[0], wred[1]), fmaxf(wred[2], wred[3])),
              fmaxf(fmaxf(wred[4], wred[5]), fmaxf(wred[6], wred[7])));

    // ---- scatter exp(p - m_c) into LDS bins (j==0 lane per row group) ----
    if (j == 0) {
#pragma unroll
        for (int s = 0; s < SUBT; ++s)
            atomicAdd(&bins[sreg[s]], __expf(pv[s] - m));
    }
    __syncthreads();

    // ---- write chunk bins + max ----
    float* bg = bins_g + ((size_t)b * CHUNKS + chunk) * SS;
    bg[t] = bins[t];
    if (t == 0) pmax[b * CHUNKS + chunk] = m;
}

// ---------------------------------------------------------------------------
// Combine: out[b,s] = (sum_c bins[b,c,s] * exp(m_c - M)) / Z,
// Z recovered as the block-wide sum of the numerators. 64 blocks x 512 thr.
// ---------------------------------------------------------------------------
__global__ __launch_bounds__(512) void combine_kernel(
    const float* __restrict__ bins_g, const float* __restrict__ pmax,
    float* __restrict__ out) {
    int b = blockIdx.x;
    int t = threadIdx.x;  // 0..511
    __shared__ float scale[CHUNKS];
    __shared__ float red[8];
    __shared__ float sInv;

    if (t < CHUNKS) scale[t] = pmax[b * CHUNKS + t];
    __syncthreads();
    if (t == 0) {
        float M = scale[0];
#pragma unroll
        for (int c = 1; c < CHUNKS; ++c) M = fmaxf(M, scale[c]);
#pragma unroll
        for (int c = 0; c < CHUNKS; ++c) scale[c] = __expf(scale[c] - M);
    }
    __syncthreads();

    float acc = 0.f;
#pragma unroll
    for (int c = 0; c < CHUNKS; ++c)
        acc = fmaf(bins_g[((size_t)b * CHUNKS + c) * SS + t], scale[c], acc);

    float s = acc;
#pragma unroll
    for (int off = 32; off > 0; off >>= 1) s += __shfl_xor(s, off, 64);
    if ((t & 63) == 0) red[t >> 6] = s;
    __syncthreads();
    if (t == 0) {
        float S = 0.f;
#pragma unroll
        for (int i = 0; i < 8; ++i) S += red[i];
        sInv = 1.f / S;
    }
    __syncthreads();

    out[b * SS + t] = acc * sInv;
}

// ---------------------------------------------------------------------------
// Launch. Inputs: [0]=s_past(int B*N), [1]=yq(f32 B*D2), [2]=y_past(f32
// B*N*D2), [3]=w_mat(f32 D2*D2), [4]=size_s. Out: post_est f32 B*S.
// ws: bins_g (B*CHUNKS*S = 2 MB) | pmax (B*CHUNKS)   [unchanged layout]
// ---------------------------------------------------------------------------
extern "C" void kernel_launch(void* const* d_in, const int* in_sizes, int n_in,
                              void* d_out, int out_size, void* d_ws, size_t ws_size,
                              hipStream_t stream) {
    const int*   s_past = (const int*)d_in[0];
    const float* yq     = (const float*)d_in[1];
    const float* y_past = (const float*)d_in[2];
    const float* w_mat  = (const float*)d_in[3];

    float* ws     = (float*)d_ws;
    float* bins_g = ws;                         // BB*CHUNKS*SS floats
    float* pmax   = bins_g + BB * CHUNKS * SS;  // BB*CHUNKS floats
    float* out    = (float*)d_out;

    fused_kernel<<<dim3(BB, CHUNKS), 512, 0, stream>>>(y_past, yq, w_mat,
                                                       s_past, bins_g, pmax);
    combine_kernel<<<BB, SS, 0, stream>>>(bins_g, pmax, out);
}